// Round 14
// baseline (360.757 us; speedup 1.0000x reference)
//
#include <hip/hip_runtime.h>

#define N_NODES 100000
#define N_EDGES 3200000
#define N_GRAPHS 512
#define NBKT 782          // coarse buckets = dst>>7  (782*128 = 100096 >= N_NODES)
#define NBLK 256          // binning blocks
#define EPB 12500         // edges per binning block: 256*12500 = 3.2M exactly
#define NSCAN 200192      // NBKT*NBLK
#define NB_SCAN 782       // ceil(NSCAN/256)
#define SCAP 6000         // LDS staging capacity for k_sortb (ints)
#define NCOPY 64          // spread-copies for BN-stats atomics (R10 lesson)
#define STREG (NCOPY * 128)   // floats per stats region

typedef short bf16x8 __attribute__((ext_vector_type(8)));
typedef float f32x4 __attribute__((ext_vector_type(4)));

__device__ __forceinline__ uint32_t f2bf(float f) {   // RNE f32->bf16
  uint32_t u = __float_as_uint(f);
  return (u + 0x7fffu + ((u >> 16) & 1u)) >> 16;
}
__device__ __forceinline__ float bflo(uint32_t u) { return __uint_as_float(u << 16); }
__device__ __forceinline__ float bfhi(uint32_t u) { return __uint_as_float(u & 0xffff0000u); }

// ---------------------------------------------------------------------------
// stage 1: per-block bucket histogram (block owns contiguous edge slice)
__global__ __launch_bounds__(256) void k_cnt(const int* __restrict__ dst,
                                             int* __restrict__ cnt)
{
  __shared__ int h[NBKT];
  int t = threadIdx.x, blk = blockIdx.x;
  for (int i = t; i < NBKT; i += 256) h[i] = 0;
  __syncthreads();
  int e0 = blk * EPB;
  for (int i = t; i < EPB; i += 256) atomicAdd(&h[dst[e0 + i] >> 7], 1);
  __syncthreads();
  for (int i = t; i < NBKT; i += 256) cnt[i * NBLK + blk] = h[i];
}

__global__ __launch_bounds__(256) void k_scan1(const int* __restrict__ v,
                                               int* __restrict__ bsum, int n)
{
  __shared__ int s[256];
  int i = blockIdx.x * 256 + threadIdx.x;
  s[threadIdx.x] = i < n ? v[i] : 0;
  __syncthreads();
  for (int off = 128; off > 0; off >>= 1) {
    if (threadIdx.x < off) s[threadIdx.x] += s[threadIdx.x + off];
    __syncthreads();
  }
  if (threadIdx.x == 0) bsum[blockIdx.x] = s[0];
}

// exclusive scan of block sums (one block, 1024 threads; nb <= 1024)
__global__ void k_scan2(int* __restrict__ bsum, int nb)
{
  __shared__ int s[1024];
  int t = threadIdx.x;
  int v = t < nb ? bsum[t] : 0;
  s[t] = v;
  __syncthreads();
  for (int off = 1; off < 1024; off <<= 1) {
    int nv = t >= off ? s[t - off] : 0;
    __syncthreads();
    s[t] += nv;
    __syncthreads();
  }
  if (t < nb) bsum[t] = s[t] - v;
}

__global__ __launch_bounds__(256) void k_scanout(const int* __restrict__ v,
    const int* __restrict__ boff, int* __restrict__ out, int n)
{
  __shared__ int s[256];
  int t = threadIdx.x, i = blockIdx.x * 256 + t;
  int x = i < n ? v[i] : 0;
  s[t] = x;
  __syncthreads();
  for (int off = 1; off < 256; off <<= 1) {
    int nv = t >= off ? s[t - off] : 0;
    __syncthreads();
    s[t] += nv;
    __syncthreads();
  }
  if (i < n) out[i] = boff[blockIdx.x] + s[t] - x;
}

// stage 2: bin edges into per-(block,bucket) private runs (LDS cursors only)
// packed: src | ((dst&127)<<17)  (src < 2^17, within-bucket key = 7 bits)
__global__ __launch_bounds__(256) void k_bin(const int* __restrict__ src,
    const int* __restrict__ dst, const int* __restrict__ off,
    int* __restrict__ eb)
{
  __shared__ int base[NBKT];
  __shared__ int cur[NBKT];
  int t = threadIdx.x, blk = blockIdx.x;
  for (int i = t; i < NBKT; i += 256) { base[i] = off[i * NBLK + blk]; cur[i] = 0; }
  __syncthreads();
  int e0 = blk * EPB;
  for (int i = t; i < EPB; i += 256) {
    int e = e0 + i;
    int s = src[e], d = dst[e], b = d >> 7;
    int p = atomicAdd(&cur[b], 1);
    eb[base[b] + p] = s | ((d & 127) << 17);
  }
}

// stage 3: per-bucket exact counting sort, LDS-staged -> csr + rowstart
__global__ __launch_bounds__(256) void k_sortb(const int* __restrict__ eb,
    const int* __restrict__ off, int* __restrict__ rowstart,
    int* __restrict__ csr)
{
  int b = blockIdx.x, t = threadIdx.x;
  int start = off[b * NBLK];
  int end = (b == NBKT - 1) ? N_EDGES : off[(b + 1) * NBLK];
  int cnt = end - start;
  __shared__ int ebs[SCAP];
  __shared__ int h[128], cur[128];
  bool staged = cnt <= SCAP;
  if (staged) for (int i = t; i < cnt; i += 256) ebs[i] = eb[start + i];
  if (t < 128) h[t] = 0;
  __syncthreads();
  if (staged) {
    for (int i = t; i < cnt; i += 256) atomicAdd(&h[(ebs[i] >> 17) & 127], 1);
  } else {
    for (int i = t; i < cnt; i += 256) atomicAdd(&h[(eb[start + i] >> 17) & 127], 1);
  }
  __syncthreads();
  int v = t < 128 ? h[t] : 0;
  for (int o = 1; o < 128; o <<= 1) {
    int nv = (t < 128 && t >= o) ? h[t - o] : 0;
    __syncthreads();
    if (t < 128) h[t] += nv;
    __syncthreads();
  }
  if (t < 128) {
    int ex = h[t] - v;
    int node = b * 128 + t;
    if (node < N_NODES) rowstart[node] = start + ex;
    cur[t] = ex;
  }
  if (b == NBKT - 1 && t == 0) rowstart[N_NODES] = N_EDGES;
  __syncthreads();
  if (staged) {
    for (int i = t; i < cnt; i += 256) {
      int e = ebs[i];
      int p = atomicAdd(&cur[(e >> 17) & 127], 1);
      csr[start + p] = e & 0x1FFFF;
    }
  } else {
    for (int i = t; i < cnt; i += 256) {
      int e = eb[start + i];
      int p = atomicAdd(&cur[(e >> 17) & 127], 1);
      csr[start + p] = e & 0x1FFFF;
    }
  }
}

// graph boundaries from sorted batch
__global__ __launch_bounds__(256) void k_gstart(const int* __restrict__ batch,
                                                int* __restrict__ gstart, int n)
{
  int i = blockIdx.x * 256 + threadIdx.x;
  if (i >= n) return;
  int b = batch[i];
  if (i == 0) {
    for (int g = 0; g <= b; ++g) gstart[g] = 0;
  } else {
    int p = batch[i - 1];
    for (int g = p + 1; g <= b; ++g) gstart[g] = i;
  }
  if (i == n - 1) {
    for (int g = b + 1; g <= N_GRAPHS; ++g) gstart[g] = n;
  }
}

// ---------------------------------------------------------------------------
// fused conv1 front: half-wave (32 lanes) per node gathers neighbor float4
// rows, shfl_xor reduce, then t1 = (x+agg)@w1^T+b1; stats spread over NCOPY.
__global__ __launch_bounds__(256) void k_agglin1(const int* __restrict__ csr,
    const int* __restrict__ rowstart, const float* __restrict__ x,
    const float* __restrict__ w1, const float* __restrict__ b1,
    float* __restrict__ OUT, float* __restrict__ st, int n)
{
  __shared__ float sAgg[8][4];
  __shared__ float rs[4][64], rq[4][64];
  int t = threadIdx.x;
  int hw = t >> 5, lane = t & 31;
  int nd = blockIdx.x * 8 + hw;
  const float4* x4 = reinterpret_cast<const float4*>(x);
  float4 a = make_float4(0.f, 0.f, 0.f, 0.f);
  if (nd < n) {
    int e0 = rowstart[nd], e1 = rowstart[nd + 1];
    for (int e = e0 + lane; e < e1; e += 32) {
      float4 v = x4[csr[e]];
      a.x += v.x; a.y += v.y; a.z += v.z; a.w += v.w;
    }
    if (lane == 0) {                       // GIN identity term
      float4 v = x4[nd];
      a.x += v.x; a.y += v.y; a.z += v.z; a.w += v.w;
    }
  }
  for (int off = 1; off < 32; off <<= 1) { // reduce within half-wave
    a.x += __shfl_xor(a.x, off);
    a.y += __shfl_xor(a.y, off);
    a.z += __shfl_xor(a.z, off);
    a.w += __shfl_xor(a.w, off);
  }
  if (lane == 0) *reinterpret_cast<float4*>(&sAgg[hw][0]) = a;
  __syncthreads();
  int d = t & 63, slot = t >> 6;
  float4 wr = reinterpret_cast<const float4*>(w1)[d];
  float bv = b1[d];
  float lsum = 0.f, lsq = 0.f;
  int base = blockIdx.x * 8;
#pragma unroll
  for (int li = slot; li < 8; li += 4) {
    int nn = base + li;
    if (nn < n) {
      float v = bv + sAgg[li][0] * wr.x + sAgg[li][1] * wr.y
                   + sAgg[li][2] * wr.z + sAgg[li][3] * wr.w;
      OUT[nn * 64 + d] = v;
      lsum += v; lsq += v * v;
    }
  }
  rs[slot][d] = lsum; rq[slot][d] = lsq;
  __syncthreads();
  if (t < 64) {
    int cp = (blockIdx.x & (NCOPY - 1)) * 128;
    atomicAdd(&st[cp + d],      rs[0][d] + rs[1][d] + rs[2][d] + rs[3][d]);
    atomicAdd(&st[cp + 64 + d], rq[0][d] + rq[1][d] + rq[2][d] + rq[3][d]);
  }
}

// ---------------------------------------------------------------------------
// streaming: h = relu(T*bn(fold(stats))); optional bf16 store; per-graph pool
template <bool WRITE_HB>
__global__ __launch_bounds__(256) void k_hpool(const float* __restrict__ T,
    const float* __restrict__ st, const float* __restrict__ gam,
    const float* __restrict__ bet, float invN, const int* __restrict__ batch,
    uint2* __restrict__ Hb, float* __restrict__ pool)
{
  __shared__ float sm[16][64];
  __shared__ int sb[16];
  __shared__ float s_ss[128];
  int t = threadIdx.x;
  int r = t >> 4, c4 = t & 15;
  int row0 = blockIdx.x * 16;
  if (t < 64) {
    float s = 0.f, q = 0.f;
#pragma unroll 8
    for (int c = 0; c < NCOPY; ++c) {
      s += st[c * 128 + t];
      q += st[c * 128 + 64 + t];
    }
    float mean = s * invN;
    float var  = q * invN - mean * mean;
    float sc   = gam[t] * rsqrtf(var + 1e-5f);
    s_ss[t] = sc;
    s_ss[64 + t] = bet[t] - mean * sc;
  }
  if (t >= 64 && t < 80) sb[t - 64] = batch[row0 + t - 64];
  __syncthreads();
  float4 v = reinterpret_cast<const float4*>(T)[(row0 + r) * 16 + c4];
  int c = c4 * 4;
  v.x = fmaxf(v.x * s_ss[c + 0] + s_ss[64 + c + 0], 0.f);
  v.y = fmaxf(v.y * s_ss[c + 1] + s_ss[64 + c + 1], 0.f);
  v.z = fmaxf(v.z * s_ss[c + 2] + s_ss[64 + c + 2], 0.f);
  v.w = fmaxf(v.w * s_ss[c + 3] + s_ss[64 + c + 3], 0.f);
  if (WRITE_HB) {
    uint2 p;
    p.x = f2bf(v.x) | (f2bf(v.y) << 16);
    p.y = f2bf(v.z) | (f2bf(v.w) << 16);
    Hb[(row0 + r) * 16 + c4] = p;
  }
  *reinterpret_cast<float4*>(&sm[r][c]) = v;
  __syncthreads();
  if (t < 64) {
    int gmin = sb[0], gmax = sb[15];
    for (int g = gmin; g <= gmax; ++g) {
      float s = 0.f;
#pragma unroll
      for (int rr = 0; rr < 16; ++rr) if (sb[rr] == g) s += sm[rr][t];
      atomicAdd(&pool[g * 64 + t], s);
    }
  }
}

// ---------------------------------------------------------------------------
// pool x (4 features) per graph
__global__ __launch_bounds__(64) void k_pool_x(const float* __restrict__ x,
    const int* __restrict__ gstart, float* __restrict__ px)
{
  int g = blockIdx.x;
  int r0 = gstart[g], r1 = gstart[g + 1];
  int f = threadIdx.x & 3, slot = threadIdx.x >> 2;
  float acc = 0.f;
  for (int r = r0 + slot; r < r1; r += 16) acc += x[r * 4 + f];
  __shared__ float red[16][4];
  red[slot][f] = acc;
  __syncthreads();
  if (threadIdx.x < 4) {
    float s = 0.f;
    for (int k = 0; k < 16; ++k) s += red[k][f];
    px[g * 4 + f] = s;
  }
}

// ---------------------------------------------------------------------------
// FUSED conv2 front: gather-aggregate (agg64b pattern, half-wave per node,
// results staged in per-wave LDS) + MFMA GEMM t = (bf16(Hb)+AGG)@W^T+bias.
// Eliminates the 25.6MB AGG write + 25.6MB read + one launch vs R13.
// One wave = 16 rows, single pass (grid covers all groups). Fragment
// layouts identical to k_gemm64 (R13-verified).
__global__ __launch_bounds__(256) void k_aggmm(const int* __restrict__ csr,
    const int* __restrict__ rowstart, const uint32_t* __restrict__ Hb,
    const float* __restrict__ W, const float* __restrict__ bias,
    float* __restrict__ OUT, float* __restrict__ st, int n)
{
  __shared__ float sA[4][16][68];     // per-wave agg staging (+4 pad)
  __shared__ float rs[4][64], rq[4][64];
  int tid = threadIdx.x;
  int wav = tid >> 6, lane = tid & 63;
  int m16 = lane & 15, kb = lane >> 4;
  int hw = lane >> 5, lane31 = lane & 31;
  // B fragments: W row (tt*16+m16), k = kh*32 + kb*8 + e
  bf16x8 Bf[4][2];
#pragma unroll
  for (int tt = 0; tt < 4; tt++)
#pragma unroll
    for (int kh = 0; kh < 2; kh++) {
      const float* wr = W + (tt * 16 + m16) * 64 + kh * 32 + kb * 8;
      float4 w0 = *reinterpret_cast<const float4*>(wr);
      float4 w1 = *reinterpret_cast<const float4*>(wr + 4);
      bf16x8 f;
      f[0] = (short)f2bf(w0.x); f[1] = (short)f2bf(w0.y);
      f[2] = (short)f2bf(w0.z); f[3] = (short)f2bf(w0.w);
      f[4] = (short)f2bf(w1.x); f[5] = (short)f2bf(w1.y);
      f[6] = (short)f2bf(w1.z); f[7] = (short)f2bf(w1.w);
      Bf[tt][kh] = f;
    }
  float bvt[4];
#pragma unroll
  for (int tt = 0; tt < 4; tt++) bvt[tt] = bias[tt * 16 + m16];
  int base = blockIdx.x * 64 + wav * 16;
  // ---- gather phase: 8 iterations of 2 nodes (half-wave per node) ----
  if (base < n) {
#pragma unroll 2
    for (int i = 0; i < 8; i++) {
      int nd = base + 2 * i + hw;
      int e = rowstart[nd], e1 = rowstart[nd + 1];
      float a0 = 0.f, a1 = 0.f;
      for (; e + 4 <= e1; e += 4) {
        int s0 = csr[e], s1 = csr[e + 1], s2 = csr[e + 2], s3 = csr[e + 3];
        uint32_t u0 = Hb[s0 * 32 + lane31];
        uint32_t u1 = Hb[s1 * 32 + lane31];
        uint32_t u2 = Hb[s2 * 32 + lane31];
        uint32_t u3 = Hb[s3 * 32 + lane31];
        a0 += bflo(u0) + bflo(u1) + bflo(u2) + bflo(u3);
        a1 += bfhi(u0) + bfhi(u1) + bfhi(u2) + bfhi(u3);
      }
      for (; e < e1; ++e) {
        uint32_t u = Hb[csr[e] * 32 + lane31];
        a0 += bflo(u); a1 += bfhi(u);
      }
      *reinterpret_cast<float2*>(&sA[wav][2 * i + hw][lane31 * 2]) =
          make_float2(a0, a1);
    }
  }
  __syncthreads();
  // ---- MFMA phase ----
  float lsum[4] = {0.f, 0.f, 0.f, 0.f}, lsq[4] = {0.f, 0.f, 0.f, 0.f};
  if (base < n) {
    int arow = base + m16;
    const uint2* in1 = reinterpret_cast<const uint2*>(Hb);
    uint2 b0 = in1[arow * 16 + kb * 2];
    uint2 b1 = in1[arow * 16 + kb * 2 + 1];
    uint2 b2 = in1[arow * 16 + 8 + kb * 2];
    uint2 b3 = in1[arow * 16 + 8 + kb * 2 + 1];
    const float* la0 = &sA[wav][m16][kb * 8];
    const float* la1 = &sA[wav][m16][32 + kb * 8];
    float av0[8], av1[8];
    av0[0] = bflo(b0.x) + la0[0]; av0[1] = bfhi(b0.x) + la0[1];
    av0[2] = bflo(b0.y) + la0[2]; av0[3] = bfhi(b0.y) + la0[3];
    av0[4] = bflo(b1.x) + la0[4]; av0[5] = bfhi(b1.x) + la0[5];
    av0[6] = bflo(b1.y) + la0[6]; av0[7] = bfhi(b1.y) + la0[7];
    av1[0] = bflo(b2.x) + la1[0]; av1[1] = bfhi(b2.x) + la1[1];
    av1[2] = bflo(b2.y) + la1[2]; av1[3] = bfhi(b2.y) + la1[3];
    av1[4] = bflo(b3.x) + la1[4]; av1[5] = bfhi(b3.x) + la1[5];
    av1[6] = bflo(b3.y) + la1[6]; av1[7] = bfhi(b3.y) + la1[7];
    bf16x8 A0, A1;
#pragma unroll
    for (int e = 0; e < 8; e++) {
      A0[e] = (short)f2bf(av0[e]);
      A1[e] = (short)f2bf(av1[e]);
    }
    f32x4 acc[4];
#pragma unroll
    for (int tt = 0; tt < 4; tt++) {
      acc[tt][0] = bvt[tt]; acc[tt][1] = bvt[tt];
      acc[tt][2] = bvt[tt]; acc[tt][3] = bvt[tt];
      acc[tt] = __builtin_amdgcn_mfma_f32_16x16x32_bf16(A0, Bf[tt][0], acc[tt], 0, 0, 0);
      acc[tt] = __builtin_amdgcn_mfma_f32_16x16x32_bf16(A1, Bf[tt][1], acc[tt], 0, 0, 0);
    }
#pragma unroll
    for (int tt = 0; tt < 4; tt++)
#pragma unroll
      for (int r = 0; r < 4; r++) {
        int row = base + kb * 4 + r;
        float v = acc[tt][r];
        OUT[row * 64 + tt * 16 + m16] = v;
        lsum[tt] += v; lsq[tt] += v * v;
      }
  }
#pragma unroll
  for (int tt = 0; tt < 4; tt++) {
    float s = lsum[tt];
    s += __shfl_xor(s, 16); s += __shfl_xor(s, 32);
    lsum[tt] = s;
    float q = lsq[tt];
    q += __shfl_xor(q, 16); q += __shfl_xor(q, 32);
    lsq[tt] = q;
  }
  if (lane < 16) {
#pragma unroll
    for (int tt = 0; tt < 4; tt++) {
      rs[wav][tt * 16 + lane] = lsum[tt];
      rq[wav][tt * 16 + lane] = lsq[tt];
    }
  }
  __syncthreads();
  if (tid < 64) {
    int cp = (blockIdx.x & (NCOPY - 1)) * 128;
    atomicAdd(&st[cp + tid],      rs[0][tid] + rs[1][tid] + rs[2][tid] + rs[3][tid]);
    atomicAdd(&st[cp + 64 + tid], rq[0][tid] + rq[1][tid] + rq[2][tid] + rq[3][tid]);
  }
}

// ---------------------------------------------------------------------------
// MFMA bf16 GEMM (R13-verified): OUT = relu(IN2*bn(fold(stats)))@W^T + bias.
template <int MODE>
__global__ __launch_bounds__(256) void k_gemm64(const void* __restrict__ IN1,
    const float* __restrict__ IN2, const float* __restrict__ stIn,
    const float* __restrict__ gam, const float* __restrict__ bet, float invN,
    const float* __restrict__ W, const float* __restrict__ bias,
    float* __restrict__ OUT, float* __restrict__ st, int n)
{
  __shared__ float s_ss[128];
  __shared__ float rs[4][64], rq[4][64];
  int tid = threadIdx.x;
  int wav = tid >> 6, lane = tid & 63;
  int m16 = lane & 15, kb = lane >> 4;     // kb in 0..3
  if (MODE == 0 && tid < 64) {             // fold NCOPY stats -> scale/shift
    float s = 0.f, q = 0.f;
#pragma unroll 8
    for (int c = 0; c < NCOPY; ++c) {
      s += stIn[c * 128 + tid];
      q += stIn[c * 128 + 64 + tid];
    }
    float mean = s * invN;
    float var  = q * invN - mean * mean;
    float sc   = gam[tid] * rsqrtf(var + 1e-5f);
    s_ss[tid] = sc;
    s_ss[64 + tid] = bet[tid] - mean * sc;
  }
  __syncthreads();
  float sc0[8], sh0[8], sc1[8], sh1[8];
  if (MODE == 0) {
#pragma unroll
    for (int e = 0; e < 8; e++) {
      sc0[e] = s_ss[kb * 8 + e];       sh0[e] = s_ss[64 + kb * 8 + e];
      sc1[e] = s_ss[32 + kb * 8 + e];  sh1[e] = s_ss[96 + kb * 8 + e];
    }
  }
  bf16x8 Bf[4][2];
#pragma unroll
  for (int tt = 0; tt < 4; tt++)
#pragma unroll
    for (int kh = 0; kh < 2; kh++) {
      const float* wr = W + (tt * 16 + m16) * 64 + kh * 32 + kb * 8;
      float4 w0 = *reinterpret_cast<const float4*>(wr);
      float4 w1 = *reinterpret_cast<const float4*>(wr + 4);
      bf16x8 f;
      f[0] = (short)f2bf(w0.x); f[1] = (short)f2bf(w0.y);
      f[2] = (short)f2bf(w0.z); f[3] = (short)f2bf(w0.w);
      f[4] = (short)f2bf(w1.x); f[5] = (short)f2bf(w1.y);
      f[6] = (short)f2bf(w1.z); f[7] = (short)f2bf(w1.w);
      Bf[tt][kh] = f;
    }
  float bvt[4];
#pragma unroll
  for (int tt = 0; tt < 4; tt++) bvt[tt] = bias[tt * 16 + m16];
  const float4* in2 = reinterpret_cast<const float4*>(IN2);
  float lsum[4] = {0.f, 0.f, 0.f, 0.f}, lsq[4] = {0.f, 0.f, 0.f, 0.f};
  int wid = blockIdx.x * 4 + wav, wstride = gridDim.x * 4;
  int ngroups = n >> 4;                    // n % 16 == 0
  for (int g = wid; g < ngroups; g += wstride) {
    int rbase = g * 16;
    int arow = rbase + m16;
    float av0[8], av1[8];
    float4 q0 = in2[arow * 16 + kb * 2];
    float4 q1 = in2[arow * 16 + kb * 2 + 1];
    float4 q2 = in2[arow * 16 + 8 + kb * 2];
    float4 q3 = in2[arow * 16 + 8 + kb * 2 + 1];
    float r0[8] = {q0.x, q0.y, q0.z, q0.w, q1.x, q1.y, q1.z, q1.w};
    float r1[8] = {q2.x, q2.y, q2.z, q2.w, q3.x, q3.y, q3.z, q3.w};
#pragma unroll
    for (int e = 0; e < 8; e++) {
      av0[e] = fmaxf(r0[e] * sc0[e] + sh0[e], 0.f);
      av1[e] = fmaxf(r1[e] * sc1[e] + sh1[e], 0.f);
    }
    bf16x8 A0, A1;
#pragma unroll
    for (int e = 0; e < 8; e++) {
      A0[e] = (short)f2bf(av0[e]);
      A1[e] = (short)f2bf(av1[e]);
    }
    f32x4 acc[4];
#pragma unroll
    for (int tt = 0; tt < 4; tt++) {
      acc[tt][0] = bvt[tt]; acc[tt][1] = bvt[tt];
      acc[tt][2] = bvt[tt]; acc[tt][3] = bvt[tt];
      acc[tt] = __builtin_amdgcn_mfma_f32_16x16x32_bf16(A0, Bf[tt][0], acc[tt], 0, 0, 0);
      acc[tt] = __builtin_amdgcn_mfma_f32_16x16x32_bf16(A1, Bf[tt][1], acc[tt], 0, 0, 0);
    }
#pragma unroll
    for (int tt = 0; tt < 4; tt++)
#pragma unroll
      for (int r = 0; r < 4; r++) {
        int row = rbase + kb * 4 + r;
        float v = acc[tt][r];
        OUT[row * 64 + tt * 16 + m16] = v;
        lsum[tt] += v; lsq[tt] += v * v;
      }
  }
#pragma unroll
  for (int tt = 0; tt < 4; tt++) {
    float s = lsum[tt];
    s += __shfl_xor(s, 16); s += __shfl_xor(s, 32);
    lsum[tt] = s;
    float q = lsq[tt];
    q += __shfl_xor(q, 16); q += __shfl_xor(q, 32);
    lsq[tt] = q;
  }
  if (lane < 16) {
#pragma unroll
    for (int tt = 0; tt < 4; tt++) {
      rs[wav][tt * 16 + lane] = lsum[tt];
      rq[wav][tt * 16 + lane] = lsq[tt];
    }
  }
  __syncthreads();
  if (tid < 64) {
    int cp = (blockIdx.x & (NCOPY - 1)) * 128;
    atomicAdd(&st[cp + tid],      rs[0][tid] + rs[1][tid] + rs[2][tid] + rs[3][tid]);
    atomicAdd(&st[cp + 64 + tid], rq[0][tid] + rq[1][tid] + rq[2][tid] + rq[3][tid]);
  }
}

// ---------------------------------------------------------------------------
// head
__global__ __launch_bounds__(64) void k_head(const float* __restrict__ px,
    const float* __restrict__ ph1, const float* __restrict__ ph2,
    const float* __restrict__ fc0w, const float* __restrict__ fc0b,
    const float* __restrict__ fc1w, const float* __restrict__ fc1b,
    const float* __restrict__ fc2w, const float* __restrict__ fc2b,
    const float* __restrict__ piw, const float* __restrict__ pib,
    const float* __restrict__ vfw, const float* __restrict__ vfb,
    float* __restrict__ out)
{
  int g = blockIdx.x, d = threadIdx.x;
  float o = fc0b[d] + fc1b[d] + fc2b[d];
  float4 pxv = reinterpret_cast<const float4*>(px)[g];
  float4 w0 = reinterpret_cast<const float4*>(fc0w)[d];
  o += pxv.x * w0.x + pxv.y * w0.y + pxv.z * w0.z + pxv.w * w0.w;
  const float4* p1 = reinterpret_cast<const float4*>(ph1) + g * 16;
  const float4* w1 = reinterpret_cast<const float4*>(fc1w) + d * 16;
  const float4* p2 = reinterpret_cast<const float4*>(ph2) + g * 16;
  const float4* w2 = reinterpret_cast<const float4*>(fc2w) + d * 16;
#pragma unroll
  for (int k = 0; k < 16; k++) {
    float4 a = p1[k], b = w1[k];
    o += a.x * b.x + a.y * b.y + a.z * b.z + a.w * b.w;
    float4 c = p2[k], e = w2[k];
    o += c.x * e.x + c.y * e.y + c.z * e.z + c.w * e.w;
  }
  __shared__ float so[64];
  so[d] = o;
  __syncthreads();
  float p = pib[d], v = vfb[d];
  const float4* sov = reinterpret_cast<const float4*>(so);
  const float4* wp = reinterpret_cast<const float4*>(piw) + d * 16;
  const float4* wv = reinterpret_cast<const float4*>(vfw) + d * 16;
#pragma unroll
  for (int k = 0; k < 16; k++) {
    float4 a = sov[k], b = wp[k], c = wv[k];
    p += a.x * b.x + a.y * b.y + a.z * b.z + a.w * b.w;
    v += a.x * c.x + a.y * c.y + a.z * c.z + a.w * c.w;
  }
  out[g * 64 + d] = fmaxf(p, 0.f);
  out[N_GRAPHS * 64 + g * 64 + d] = fmaxf(v, 0.f);
}

// ---------------------------------------------------------------------------
extern "C" void kernel_launch(void* const* d_in, const int* in_sizes, int n_in,
                              void* d_out, int out_size, void* d_ws, size_t ws_size,
                              hipStream_t stream)
{
  const float* x     = (const float*)d_in[0];
  const int*   ei    = (const int*)d_in[1];
  const int*   batch = (const int*)d_in[2];
  const float* c1_w1 = (const float*)d_in[3];
  const float* c1_b1 = (const float*)d_in[4];
  const float* c1_g1 = (const float*)d_in[5];
  const float* c1_be1= (const float*)d_in[6];
  const float* c1_w2 = (const float*)d_in[7];
  const float* c1_b2 = (const float*)d_in[8];
  const float* bn1_g = (const float*)d_in[9];
  const float* bn1_b = (const float*)d_in[10];
  const float* c2_w1 = (const float*)d_in[11];
  const float* c2_b1 = (const float*)d_in[12];
  const float* c2_g1 = (const float*)d_in[13];
  const float* c2_be1= (const float*)d_in[14];
  const float* c2_w2 = (const float*)d_in[15];
  const float* c2_b2 = (const float*)d_in[16];
  const float* bn2_g = (const float*)d_in[17];
  const float* bn2_b = (const float*)d_in[18];
  const float* fc0_w = (const float*)d_in[19];
  const float* fc0_b = (const float*)d_in[20];
  const float* fc1_w = (const float*)d_in[21];
  const float* fc1_b = (const float*)d_in[22];
  const float* fc2_w = (const float*)d_in[23];
  const float* fc2_b = (const float*)d_in[24];
  const float* pi_w  = (const float*)d_in[25];
  const float* pi_b  = (const float*)d_in[26];
  const float* vf_w  = (const float*)d_in[27];
  const float* vf_b  = (const float*)d_in[28];
  const int* src = ei;
  const int* dst = ei + N_EDGES;

  float* ws = (float*)d_ws;
  // layout (float offsets, 16B aligned). zeroed prefix: [stats(4xSTREG)|ph1|ph2]
  float* stats    = ws;                          // 4 x 8192 = 32768
  float* ph1      = ws + 32768;                  // 32768
  float* ph2      = ws + 65536;                  // 32768  (prefix ends 98304)
  float* px       = ws + 98304;                  // 2048
  int*   gstart   = (int*)(ws + 100352);         // 513 -> pad 100880
  int*   bsum     = (int*)(ws + 100880);         // 1024 -> pad 101920
  int*   rowstart = (int*)(ws + 101920);         // 100001 -> pad 201936
  float* U        = ws + 201936;                 // union: {cnt,off} then Hb (3.2M)
  int*   cnt      = (int*)U;                     // 200192
  int*   off      = (int*)U + 200192;            // 200192
  uint32_t* Hb    = (uint32_t*)U;                // 100000 x 32 u32 (bf16 pairs), linear
  int*   csr      = (int*)(ws + 3401936);        // 3200000
  float* A        = ws + 6601936;                // N x 64 (eb aliases: 3.2M int)
  int*   eb       = (int*)A;                     // end 13,001,936 fl = 52 MB

  const float invN = 1.0f / (float)N_NODES;

  hipMemsetAsync(ws, 0, 98304 * sizeof(float), stream);   // stats + ph1 + ph2

  // ---- CSR build ----
  k_cnt    <<<NBLK, 256, 0, stream>>>(dst, cnt);
  k_scan1  <<<NB_SCAN, 256, 0, stream>>>(cnt, bsum, NSCAN);
  k_scan2  <<<1, 1024, 0, stream>>>(bsum, NB_SCAN);
  k_scanout<<<NB_SCAN, 256, 0, stream>>>(cnt, bsum, off, NSCAN);
  k_bin    <<<NBLK, 256, 0, stream>>>(src, dst, off, eb);
  k_sortb  <<<NBKT, 256, 0, stream>>>(eb, off, rowstart, csr);
  k_gstart <<<(N_NODES + 255) / 256, 256, 0, stream>>>(batch, gstart, N_NODES);

  // ---- pool of x ----
  k_pool_x<<<N_GRAPHS, 64, 0, stream>>>(x, gstart, px);

  // ---- conv1 (in-place on A) ----
  k_agglin1<<<N_NODES / 8, 256, 0, stream>>>(csr, rowstart, x, c1_w1, c1_b1,
                                             A, stats + 0 * STREG, N_NODES);
  k_gemm64<0><<<1563, 256, 0, stream>>>(nullptr, A, stats + 0 * STREG,
      c1_g1, c1_be1, invN, c1_w2, c1_b2, A, stats + 1 * STREG, N_NODES);
  k_hpool<true><<<N_NODES / 16, 256, 0, stream>>>(A, stats + 1 * STREG, bn1_g, bn1_b,
      invN, batch, (uint2*)Hb, ph1);

  // ---- conv2: fused gather+GEMM writes A, then gemm<0> in-place on A ----
  k_aggmm<<<(N_NODES + 63) / 64, 256, 0, stream>>>(csr, rowstart, Hb,
      c2_w1, c2_b1, A, stats + 2 * STREG, N_NODES);
  k_gemm64<0><<<1563, 256, 0, stream>>>(nullptr, A, stats + 2 * STREG,
      c2_g1, c2_be1, invN, c2_w2, c2_b2, A, stats + 3 * STREG, N_NODES);
  k_hpool<false><<<N_NODES / 16, 256, 0, stream>>>(A, stats + 3 * STREG, bn2_g, bn2_b,
      invN, batch, nullptr, ph2);

  // ---- heads ----
  k_head<<<N_GRAPHS, 64, 0, stream>>>(px, ph1, ph2, fc0_w, fc0_b, fc1_w, fc1_b,
                                      fc2_w, fc2_b, pi_w, pi_b, vf_w, vf_b, (float*)d_out);
}

// Round 15
// 327.202 us; speedup vs baseline: 1.1026x; 1.1026x over previous
//
#include <hip/hip_runtime.h>

#define N_NODES 100000
#define N_EDGES 3200000
#define N_GRAPHS 512
#define NBKT 782          // coarse buckets = dst>>7  (782*128 = 100096 >= N_NODES)
#define NBLK 256          // binning blocks
#define EPB 12500         // edges per binning block: 256*12500 = 3.2M exactly
#define NSCAN 200192      // NBKT*NBLK
#define NB_SCAN 782       // ceil(NSCAN/256)
#define SCAP 6000         // LDS staging capacity for k_sortb (ints)
#define NCOPY 64          // spread-copies for BN-stats atomics (R10 lesson)
#define STREG (NCOPY * 128)   // floats per stats region

typedef short bf16x8 __attribute__((ext_vector_type(8)));
typedef float f32x4 __attribute__((ext_vector_type(4)));

__device__ __forceinline__ uint32_t f2bf(float f) {   // RNE f32->bf16
  uint32_t u = __float_as_uint(f);
  return (u + 0x7fffu + ((u >> 16) & 1u)) >> 16;
}
__device__ __forceinline__ float bflo(uint32_t u) { return __uint_as_float(u << 16); }
__device__ __forceinline__ float bfhi(uint32_t u) { return __uint_as_float(u & 0xffff0000u); }

// ---------------------------------------------------------------------------
// stage 1: per-block bucket histogram (block owns contiguous edge slice)
__global__ __launch_bounds__(256) void k_cnt(const int* __restrict__ dst,
                                             int* __restrict__ cnt)
{
  __shared__ int h[NBKT];
  int t = threadIdx.x, blk = blockIdx.x;
  for (int i = t; i < NBKT; i += 256) h[i] = 0;
  __syncthreads();
  int e0 = blk * EPB;
  for (int i = t; i < EPB; i += 256) atomicAdd(&h[dst[e0 + i] >> 7], 1);
  __syncthreads();
  for (int i = t; i < NBKT; i += 256) cnt[i * NBLK + blk] = h[i];
}

__global__ __launch_bounds__(256) void k_scan1(const int* __restrict__ v,
                                               int* __restrict__ bsum, int n)
{
  __shared__ int s[256];
  int i = blockIdx.x * 256 + threadIdx.x;
  s[threadIdx.x] = i < n ? v[i] : 0;
  __syncthreads();
  for (int off = 128; off > 0; off >>= 1) {
    if (threadIdx.x < off) s[threadIdx.x] += s[threadIdx.x + off];
    __syncthreads();
  }
  if (threadIdx.x == 0) bsum[blockIdx.x] = s[0];
}

// exclusive scan of block sums (one block, 1024 threads; nb <= 1024)
__global__ void k_scan2(int* __restrict__ bsum, int nb)
{
  __shared__ int s[1024];
  int t = threadIdx.x;
  int v = t < nb ? bsum[t] : 0;
  s[t] = v;
  __syncthreads();
  for (int off = 1; off < 1024; off <<= 1) {
    int nv = t >= off ? s[t - off] : 0;
    __syncthreads();
    s[t] += nv;
    __syncthreads();
  }
  if (t < nb) bsum[t] = s[t] - v;
}

__global__ __launch_bounds__(256) void k_scanout(const int* __restrict__ v,
    const int* __restrict__ boff, int* __restrict__ out, int n)
{
  __shared__ int s[256];
  int t = threadIdx.x, i = blockIdx.x * 256 + t;
  int x = i < n ? v[i] : 0;
  s[t] = x;
  __syncthreads();
  for (int off = 1; off < 256; off <<= 1) {
    int nv = t >= off ? s[t - off] : 0;
    __syncthreads();
    s[t] += nv;
    __syncthreads();
  }
  if (i < n) out[i] = boff[blockIdx.x] + s[t] - x;
}

// stage 2: bin edges into per-(block,bucket) private runs (LDS cursors only)
// packed: src | ((dst&127)<<17)  (src < 2^17, within-bucket key = 7 bits)
__global__ __launch_bounds__(256) void k_bin(const int* __restrict__ src,
    const int* __restrict__ dst, const int* __restrict__ off,
    int* __restrict__ eb)
{
  __shared__ int base[NBKT];
  __shared__ int cur[NBKT];
  int t = threadIdx.x, blk = blockIdx.x;
  for (int i = t; i < NBKT; i += 256) { base[i] = off[i * NBLK + blk]; cur[i] = 0; }
  __syncthreads();
  int e0 = blk * EPB;
  for (int i = t; i < EPB; i += 256) {
    int e = e0 + i;
    int s = src[e], d = dst[e], b = d >> 7;
    int p = atomicAdd(&cur[b], 1);
    eb[base[b] + p] = s | ((d & 127) << 17);
  }
}

// stage 3: per-bucket exact counting sort, LDS-staged -> csr + rowstart
__global__ __launch_bounds__(256) void k_sortb(const int* __restrict__ eb,
    const int* __restrict__ off, int* __restrict__ rowstart,
    int* __restrict__ csr)
{
  int b = blockIdx.x, t = threadIdx.x;
  int start = off[b * NBLK];
  int end = (b == NBKT - 1) ? N_EDGES : off[(b + 1) * NBLK];
  int cnt = end - start;
  __shared__ int ebs[SCAP];
  __shared__ int h[128], cur[128];
  bool staged = cnt <= SCAP;
  if (staged) for (int i = t; i < cnt; i += 256) ebs[i] = eb[start + i];
  if (t < 128) h[t] = 0;
  __syncthreads();
  if (staged) {
    for (int i = t; i < cnt; i += 256) atomicAdd(&h[(ebs[i] >> 17) & 127], 1);
  } else {
    for (int i = t; i < cnt; i += 256) atomicAdd(&h[(eb[start + i] >> 17) & 127], 1);
  }
  __syncthreads();
  int v = t < 128 ? h[t] : 0;
  for (int o = 1; o < 128; o <<= 1) {
    int nv = (t < 128 && t >= o) ? h[t - o] : 0;
    __syncthreads();
    if (t < 128) h[t] += nv;
    __syncthreads();
  }
  if (t < 128) {
    int ex = h[t] - v;
    int node = b * 128 + t;
    if (node < N_NODES) rowstart[node] = start + ex;
    cur[t] = ex;
  }
  if (b == NBKT - 1 && t == 0) rowstart[N_NODES] = N_EDGES;
  __syncthreads();
  if (staged) {
    for (int i = t; i < cnt; i += 256) {
      int e = ebs[i];
      int p = atomicAdd(&cur[(e >> 17) & 127], 1);
      csr[start + p] = e & 0x1FFFF;
    }
  } else {
    for (int i = t; i < cnt; i += 256) {
      int e = eb[start + i];
      int p = atomicAdd(&cur[(e >> 17) & 127], 1);
      csr[start + p] = e & 0x1FFFF;
    }
  }
}

// graph boundaries from sorted batch
__global__ __launch_bounds__(256) void k_gstart(const int* __restrict__ batch,
                                                int* __restrict__ gstart, int n)
{
  int i = blockIdx.x * 256 + threadIdx.x;
  if (i >= n) return;
  int b = batch[i];
  if (i == 0) {
    for (int g = 0; g <= b; ++g) gstart[g] = 0;
  } else {
    int p = batch[i - 1];
    for (int g = p + 1; g <= b; ++g) gstart[g] = i;
  }
  if (i == n - 1) {
    for (int g = b + 1; g <= N_GRAPHS; ++g) gstart[g] = n;
  }
}

// ---------------------------------------------------------------------------
// fused conv1 front: half-wave (32 lanes) per node gathers neighbor float4
// rows, shfl_xor reduce, then t1 = (x+agg)@w1^T+b1; stats spread over NCOPY.
__global__ __launch_bounds__(256) void k_agglin1(const int* __restrict__ csr,
    const int* __restrict__ rowstart, const float* __restrict__ x,
    const float* __restrict__ w1, const float* __restrict__ b1,
    float* __restrict__ OUT, float* __restrict__ st, int n)
{
  __shared__ float sAgg[8][4];
  __shared__ float rs[4][64], rq[4][64];
  int t = threadIdx.x;
  int hw = t >> 5, lane = t & 31;
  int nd = blockIdx.x * 8 + hw;
  const float4* x4 = reinterpret_cast<const float4*>(x);
  float4 a = make_float4(0.f, 0.f, 0.f, 0.f);
  if (nd < n) {
    int e0 = rowstart[nd], e1 = rowstart[nd + 1];
    for (int e = e0 + lane; e < e1; e += 32) {
      float4 v = x4[csr[e]];
      a.x += v.x; a.y += v.y; a.z += v.z; a.w += v.w;
    }
    if (lane == 0) {                       // GIN identity term
      float4 v = x4[nd];
      a.x += v.x; a.y += v.y; a.z += v.z; a.w += v.w;
    }
  }
  for (int off = 1; off < 32; off <<= 1) { // reduce within half-wave
    a.x += __shfl_xor(a.x, off);
    a.y += __shfl_xor(a.y, off);
    a.z += __shfl_xor(a.z, off);
    a.w += __shfl_xor(a.w, off);
  }
  if (lane == 0) *reinterpret_cast<float4*>(&sAgg[hw][0]) = a;
  __syncthreads();
  int d = t & 63, slot = t >> 6;
  float4 wr = reinterpret_cast<const float4*>(w1)[d];
  float bv = b1[d];
  float lsum = 0.f, lsq = 0.f;
  int base = blockIdx.x * 8;
#pragma unroll
  for (int li = slot; li < 8; li += 4) {
    int nn = base + li;
    if (nn < n) {
      float v = bv + sAgg[li][0] * wr.x + sAgg[li][1] * wr.y
                   + sAgg[li][2] * wr.z + sAgg[li][3] * wr.w;
      OUT[nn * 64 + d] = v;
      lsum += v; lsq += v * v;
    }
  }
  rs[slot][d] = lsum; rq[slot][d] = lsq;
  __syncthreads();
  if (t < 64) {
    int cp = (blockIdx.x & (NCOPY - 1)) * 128;
    atomicAdd(&st[cp + d],      rs[0][d] + rs[1][d] + rs[2][d] + rs[3][d]);
    atomicAdd(&st[cp + 64 + d], rq[0][d] + rq[1][d] + rq[2][d] + rq[3][d]);
  }
}

// ---------------------------------------------------------------------------
// streaming: h = relu(T*bn(fold(stats))); optional bf16 store; per-graph pool
template <bool WRITE_HB>
__global__ __launch_bounds__(256) void k_hpool(const float* __restrict__ T,
    const float* __restrict__ st, const float* __restrict__ gam,
    const float* __restrict__ bet, float invN, const int* __restrict__ batch,
    uint2* __restrict__ Hb, float* __restrict__ pool)
{
  __shared__ float sm[16][64];
  __shared__ int sb[16];
  __shared__ float s_ss[128];
  int t = threadIdx.x;
  int r = t >> 4, c4 = t & 15;
  int row0 = blockIdx.x * 16;
  if (t < 64) {
    float s = 0.f, q = 0.f;
#pragma unroll 8
    for (int c = 0; c < NCOPY; ++c) {
      s += st[c * 128 + t];
      q += st[c * 128 + 64 + t];
    }
    float mean = s * invN;
    float var  = q * invN - mean * mean;
    float sc   = gam[t] * rsqrtf(var + 1e-5f);
    s_ss[t] = sc;
    s_ss[64 + t] = bet[t] - mean * sc;
  }
  if (t >= 64 && t < 80) sb[t - 64] = batch[row0 + t - 64];
  __syncthreads();
  float4 v = reinterpret_cast<const float4*>(T)[(row0 + r) * 16 + c4];
  int c = c4 * 4;
  v.x = fmaxf(v.x * s_ss[c + 0] + s_ss[64 + c + 0], 0.f);
  v.y = fmaxf(v.y * s_ss[c + 1] + s_ss[64 + c + 1], 0.f);
  v.z = fmaxf(v.z * s_ss[c + 2] + s_ss[64 + c + 2], 0.f);
  v.w = fmaxf(v.w * s_ss[c + 3] + s_ss[64 + c + 3], 0.f);
  if (WRITE_HB) {
    uint2 p;
    p.x = f2bf(v.x) | (f2bf(v.y) << 16);
    p.y = f2bf(v.z) | (f2bf(v.w) << 16);
    Hb[(row0 + r) * 16 + c4] = p;
  }
  *reinterpret_cast<float4*>(&sm[r][c]) = v;
  __syncthreads();
  if (t < 64) {
    int gmin = sb[0], gmax = sb[15];
    for (int g = gmin; g <= gmax; ++g) {
      float s = 0.f;
#pragma unroll
      for (int rr = 0; rr < 16; ++rr) if (sb[rr] == g) s += sm[rr][t];
      atomicAdd(&pool[g * 64 + t], s);
    }
  }
}

// ---------------------------------------------------------------------------
// gather-aggregate from bf16 table: half-wave per node, lane = u32 (2 feats)
__global__ __launch_bounds__(256) void k_agg64b(const int* __restrict__ csr,
    const int* __restrict__ rowstart, const uint32_t* __restrict__ Hb,
    float2* __restrict__ AGG, int n)
{
  int hw = threadIdx.x >> 5, lane = threadIdx.x & 31;
  int nd = blockIdx.x * 8 + hw;
  if (nd >= n) return;
  int e = rowstart[nd], e1 = rowstart[nd + 1];
  float a0 = 0.f, a1 = 0.f;
  for (; e + 4 <= e1; e += 4) {
    int s0 = csr[e], s1 = csr[e + 1], s2 = csr[e + 2], s3 = csr[e + 3];
    uint32_t u0 = Hb[s0 * 32 + lane];
    uint32_t u1 = Hb[s1 * 32 + lane];
    uint32_t u2 = Hb[s2 * 32 + lane];
    uint32_t u3 = Hb[s3 * 32 + lane];
    a0 += bflo(u0) + bflo(u1) + bflo(u2) + bflo(u3);
    a1 += bfhi(u0) + bfhi(u1) + bfhi(u2) + bfhi(u3);
  }
  for (; e < e1; ++e) {
    uint32_t u = Hb[csr[e] * 32 + lane];
    a0 += bflo(u); a1 += bfhi(u);
  }
  AGG[nd * 32 + lane] = make_float2(a0, a1);
}

// ---------------------------------------------------------------------------
// pool x (4 features) per graph
__global__ __launch_bounds__(64) void k_pool_x(const float* __restrict__ x,
    const int* __restrict__ gstart, float* __restrict__ px)
{
  int g = blockIdx.x;
  int r0 = gstart[g], r1 = gstart[g + 1];
  int f = threadIdx.x & 3, slot = threadIdx.x >> 2;
  float acc = 0.f;
  for (int r = r0 + slot; r < r1; r += 16) acc += x[r * 4 + f];
  __shared__ float red[16][4];
  red[slot][f] = acc;
  __syncthreads();
  if (threadIdx.x < 4) {
    float s = 0.f;
    for (int k = 0; k < 16; ++k) s += red[k][f];
    px[g * 4 + f] = s;
  }
}

// ---------------------------------------------------------------------------
// MFMA bf16 GEMM (R13-verified): OUT = f(...) @ W^T + bias; stats spread-accum.
// Per wave: 16 rows x 64 cols = 4 C-tiles of 16x16, K=64 via 2x
// mfma_f32_16x16x32_bf16. A[m][k]: lane = m + 16*(k/8), elem k%8;
// B[k][n]: lane = n + 16*(k/8), elem k%8 (B[k][n] = W[n][k]);
// C/D: col=lane&15, row=(lane>>4)*4+reg (m89-verified).
// MODE 0: f = relu(IN2 * bn(fold(stats)));  MODE 2: f = bf16(IN1) + IN2.
// R14 lesson: do NOT fuse the gather into this kernel — fusion cut occupancy
// 75->33% and gather BW 3.6->2.2 TB/s (335->361us).
template <int MODE>
__global__ __launch_bounds__(256) void k_gemm64(const void* __restrict__ IN1,
    const float* __restrict__ IN2, const float* __restrict__ stIn,
    const float* __restrict__ gam, const float* __restrict__ bet, float invN,
    const float* __restrict__ W, const float* __restrict__ bias,
    float* __restrict__ OUT, float* __restrict__ st, int n)
{
  __shared__ float s_ss[128];
  __shared__ float rs[4][64], rq[4][64];
  int tid = threadIdx.x;
  int wav = tid >> 6, lane = tid & 63;
  int m16 = lane & 15, kb = lane >> 4;     // kb in 0..3
  if (MODE == 0 && tid < 64) {             // fold NCOPY stats -> scale/shift
    float s = 0.f, q = 0.f;
#pragma unroll 8
    for (int c = 0; c < NCOPY; ++c) {
      s += stIn[c * 128 + tid];
      q += stIn[c * 128 + 64 + tid];
    }
    float mean = s * invN;
    float var  = q * invN - mean * mean;
    float sc   = gam[tid] * rsqrtf(var + 1e-5f);
    s_ss[tid] = sc;
    s_ss[64 + tid] = bet[tid] - mean * sc;
  }
  __syncthreads();
  // BN params for this lane's A-element k positions
  float sc0[8], sh0[8], sc1[8], sh1[8];
  if (MODE == 0) {
#pragma unroll
    for (int e = 0; e < 8; e++) {
      sc0[e] = s_ss[kb * 8 + e];       sh0[e] = s_ss[64 + kb * 8 + e];
      sc1[e] = s_ss[32 + kb * 8 + e];  sh1[e] = s_ss[96 + kb * 8 + e];
    }
  }
  // B fragments: tile t (cols t*16..+15), k-half kh: lane holds W[t*16+m16][kh*32+kb*8+e]
  bf16x8 Bf[4][2];
#pragma unroll
  for (int tt = 0; tt < 4; tt++)
#pragma unroll
    for (int kh = 0; kh < 2; kh++) {
      const float* wr = W + (tt * 16 + m16) * 64 + kh * 32 + kb * 8;
      float4 w0 = *reinterpret_cast<const float4*>(wr);
      float4 w1 = *reinterpret_cast<const float4*>(wr + 4);
      bf16x8 f;
      f[0] = (short)f2bf(w0.x); f[1] = (short)f2bf(w0.y);
      f[2] = (short)f2bf(w0.z); f[3] = (short)f2bf(w0.w);
      f[4] = (short)f2bf(w1.x); f[5] = (short)f2bf(w1.y);
      f[6] = (short)f2bf(w1.z); f[7] = (short)f2bf(w1.w);
      Bf[tt][kh] = f;
    }
  float bvt[4];
#pragma unroll
  for (int tt = 0; tt < 4; tt++) bvt[tt] = bias[tt * 16 + m16];
  const float4* in2 = reinterpret_cast<const float4*>(IN2);
  const uint2*  in1 = reinterpret_cast<const uint2*>(IN1);
  float lsum[4] = {0.f, 0.f, 0.f, 0.f}, lsq[4] = {0.f, 0.f, 0.f, 0.f};
  int wid = blockIdx.x * 4 + wav, wstride = gridDim.x * 4;
  int ngroups = n >> 4;                    // n % 16 == 0
  for (int g = wid; g < ngroups; g += wstride) {
    int rbase = g * 16;
    int arow = rbase + m16;
    float av0[8], av1[8];
    if (MODE == 0) {
      float4 q0 = in2[arow * 16 + kb * 2];
      float4 q1 = in2[arow * 16 + kb * 2 + 1];
      float4 q2 = in2[arow * 16 + 8 + kb * 2];
      float4 q3 = in2[arow * 16 + 8 + kb * 2 + 1];
      float r0[8] = {q0.x, q0.y, q0.z, q0.w, q1.x, q1.y, q1.z, q1.w};
      float r1[8] = {q2.x, q2.y, q2.z, q2.w, q3.x, q3.y, q3.z, q3.w};
#pragma unroll
      for (int e = 0; e < 8; e++) {
        av0[e] = fmaxf(r0[e] * sc0[e] + sh0[e], 0.f);
        av1[e] = fmaxf(r1[e] * sc1[e] + sh1[e], 0.f);
      }
    } else {
      uint2 b0 = in1[arow * 16 + kb * 2];
      uint2 b1 = in1[arow * 16 + kb * 2 + 1];
      uint2 b2 = in1[arow * 16 + 8 + kb * 2];
      uint2 b3 = in1[arow * 16 + 8 + kb * 2 + 1];
      float4 g0 = in2[arow * 16 + kb * 2];
      float4 g1 = in2[arow * 16 + kb * 2 + 1];
      float4 g2 = in2[arow * 16 + 8 + kb * 2];
      float4 g3 = in2[arow * 16 + 8 + kb * 2 + 1];
      av0[0] = bflo(b0.x) + g0.x; av0[1] = bfhi(b0.x) + g0.y;
      av0[2] = bflo(b0.y) + g0.z; av0[3] = bfhi(b0.y) + g0.w;
      av0[4] = bflo(b1.x) + g1.x; av0[5] = bfhi(b1.x) + g1.y;
      av0[6] = bflo(b1.y) + g1.z; av0[7] = bfhi(b1.y) + g1.w;
      av1[0] = bflo(b2.x) + g2.x; av1[1] = bfhi(b2.x) + g2.y;
      av1[2] = bflo(b2.y) + g2.z; av1[3] = bfhi(b2.y) + g2.w;
      av1[4] = bflo(b3.x) + g3.x; av1[5] = bfhi(b3.x) + g3.y;
      av1[6] = bflo(b3.y) + g3.z; av1[7] = bfhi(b3.y) + g3.w;
    }
    bf16x8 A0, A1;
#pragma unroll
    for (int e = 0; e < 8; e++) {
      A0[e] = (short)f2bf(av0[e]);
      A1[e] = (short)f2bf(av1[e]);
    }
    f32x4 acc[4];
#pragma unroll
    for (int tt = 0; tt < 4; tt++) {
      acc[tt][0] = bvt[tt]; acc[tt][1] = bvt[tt];
      acc[tt][2] = bvt[tt]; acc[tt][3] = bvt[tt];
      acc[tt] = __builtin_amdgcn_mfma_f32_16x16x32_bf16(A0, Bf[tt][0], acc[tt], 0, 0, 0);
      acc[tt] = __builtin_amdgcn_mfma_f32_16x16x32_bf16(A1, Bf[tt][1], acc[tt], 0, 0, 0);
    }
#pragma unroll
    for (int tt = 0; tt < 4; tt++)
#pragma unroll
      for (int r = 0; r < 4; r++) {
        int row = rbase + kb * 4 + r;
        float v = acc[tt][r];
        OUT[row * 64 + tt * 16 + m16] = v;
        lsum[tt] += v; lsq[tt] += v * v;
      }
  }
  // reduce stats across the 4 kb-groups (same column in lanes l, l^16, l^32)
#pragma unroll
  for (int tt = 0; tt < 4; tt++) {
    float s = lsum[tt];
    s += __shfl_xor(s, 16); s += __shfl_xor(s, 32);
    lsum[tt] = s;
    float q = lsq[tt];
    q += __shfl_xor(q, 16); q += __shfl_xor(q, 32);
    lsq[tt] = q;
  }
  if (lane < 16) {
#pragma unroll
    for (int tt = 0; tt < 4; tt++) {
      rs[wav][tt * 16 + lane] = lsum[tt];
      rq[wav][tt * 16 + lane] = lsq[tt];
    }
  }
  __syncthreads();
  if (tid < 64) {
    int cp = (blockIdx.x & (NCOPY - 1)) * 128;
    atomicAdd(&st[cp + tid],      rs[0][tid] + rs[1][tid] + rs[2][tid] + rs[3][tid]);
    atomicAdd(&st[cp + 64 + tid], rq[0][tid] + rq[1][tid] + rq[2][tid] + rq[3][tid]);
  }
}

// ---------------------------------------------------------------------------
// head
__global__ __launch_bounds__(64) void k_head(const float* __restrict__ px,
    const float* __restrict__ ph1, const float* __restrict__ ph2,
    const float* __restrict__ fc0w, const float* __restrict__ fc0b,
    const float* __restrict__ fc1w, const float* __restrict__ fc1b,
    const float* __restrict__ fc2w, const float* __restrict__ fc2b,
    const float* __restrict__ piw, const float* __restrict__ pib,
    const float* __restrict__ vfw, const float* __restrict__ vfb,
    float* __restrict__ out)
{
  int g = blockIdx.x, d = threadIdx.x;
  float o = fc0b[d] + fc1b[d] + fc2b[d];
  float4 pxv = reinterpret_cast<const float4*>(px)[g];
  float4 w0 = reinterpret_cast<const float4*>(fc0w)[d];
  o += pxv.x * w0.x + pxv.y * w0.y + pxv.z * w0.z + pxv.w * w0.w;
  const float4* p1 = reinterpret_cast<const float4*>(ph1) + g * 16;
  const float4* w1 = reinterpret_cast<const float4*>(fc1w) + d * 16;
  const float4* p2 = reinterpret_cast<const float4*>(ph2) + g * 16;
  const float4* w2 = reinterpret_cast<const float4*>(fc2w) + d * 16;
#pragma unroll
  for (int k = 0; k < 16; k++) {
    float4 a = p1[k], b = w1[k];
    o += a.x * b.x + a.y * b.y + a.z * b.z + a.w * b.w;
    float4 c = p2[k], e = w2[k];
    o += c.x * e.x + c.y * e.y + c.z * e.z + c.w * e.w;
  }
  __shared__ float so[64];
  so[d] = o;
  __syncthreads();
  float p = pib[d], v = vfb[d];
  const float4* sov = reinterpret_cast<const float4*>(so);
  const float4* wp = reinterpret_cast<const float4*>(piw) + d * 16;
  const float4* wv = reinterpret_cast<const float4*>(vfw) + d * 16;
#pragma unroll
  for (int k = 0; k < 16; k++) {
    float4 a = sov[k], b = wp[k], c = wv[k];
    p += a.x * b.x + a.y * b.y + a.z * b.z + a.w * b.w;
    v += a.x * c.x + a.y * c.y + a.z * c.z + a.w * c.w;
  }
  out[g * 64 + d] = fmaxf(p, 0.f);
  out[N_GRAPHS * 64 + g * 64 + d] = fmaxf(v, 0.f);
}

// ---------------------------------------------------------------------------
extern "C" void kernel_launch(void* const* d_in, const int* in_sizes, int n_in,
                              void* d_out, int out_size, void* d_ws, size_t ws_size,
                              hipStream_t stream)
{
  const float* x     = (const float*)d_in[0];
  const int*   ei    = (const int*)d_in[1];
  const int*   batch = (const int*)d_in[2];
  const float* c1_w1 = (const float*)d_in[3];
  const float* c1_b1 = (const float*)d_in[4];
  const float* c1_g1 = (const float*)d_in[5];
  const float* c1_be1= (const float*)d_in[6];
  const float* c1_w2 = (const float*)d_in[7];
  const float* c1_b2 = (const float*)d_in[8];
  const float* bn1_g = (const float*)d_in[9];
  const float* bn1_b = (const float*)d_in[10];
  const float* c2_w1 = (const float*)d_in[11];
  const float* c2_b1 = (const float*)d_in[12];
  const float* c2_g1 = (const float*)d_in[13];
  const float* c2_be1= (const float*)d_in[14];
  const float* c2_w2 = (const float*)d_in[15];
  const float* c2_b2 = (const float*)d_in[16];
  const float* bn2_g = (const float*)d_in[17];
  const float* bn2_b = (const float*)d_in[18];
  const float* fc0_w = (const float*)d_in[19];
  const float* fc0_b = (const float*)d_in[20];
  const float* fc1_w = (const float*)d_in[21];
  const float* fc1_b = (const float*)d_in[22];
  const float* fc2_w = (const float*)d_in[23];
  const float* fc2_b = (const float*)d_in[24];
  const float* pi_w  = (const float*)d_in[25];
  const float* pi_b  = (const float*)d_in[26];
  const float* vf_w  = (const float*)d_in[27];
  const float* vf_b  = (const float*)d_in[28];
  const int* src = ei;
  const int* dst = ei + N_EDGES;

  float* ws = (float*)d_ws;
  // layout (float offsets, 16B aligned). zeroed prefix: [stats(4xSTREG)|ph1|ph2]
  float* stats    = ws;                          // 4 x 8192 = 32768
  float* ph1      = ws + 32768;                  // 32768
  float* ph2      = ws + 65536;                  // 32768  (prefix ends 98304)
  float* px       = ws + 98304;                  // 2048
  int*   gstart   = (int*)(ws + 100352);         // 513 -> pad 100880
  int*   bsum     = (int*)(ws + 100880);         // 1024 -> pad 101920
  int*   rowstart = (int*)(ws + 101920);         // 100001 -> pad 201936
  float* U        = ws + 201936;                 // union: {cnt,off} then Hb (3.2M)
  int*   cnt      = (int*)U;                     // 200192
  int*   off      = (int*)U + 200192;            // 200192
  uint32_t* Hb    = (uint32_t*)U;                // 100000 x 32 u32 (bf16 pairs), linear
  int*   csr      = (int*)(ws + 3401936);        // 3200000
  float* A        = ws + 6601936;                // N x 64 (eb aliases: 3.2M int)
  int*   eb       = (int*)A;                     // end 13,001,936 fl = 52 MB

  const float invN = 1.0f / (float)N_NODES;

  hipMemsetAsync(ws, 0, 98304 * sizeof(float), stream);   // stats + ph1 + ph2

  // ---- CSR build ----
  k_cnt    <<<NBLK, 256, 0, stream>>>(dst, cnt);
  k_scan1  <<<NB_SCAN, 256, 0, stream>>>(cnt, bsum, NSCAN);
  k_scan2  <<<1, 1024, 0, stream>>>(bsum, NB_SCAN);
  k_scanout<<<NB_SCAN, 256, 0, stream>>>(cnt, bsum, off, NSCAN);
  k_bin    <<<NBLK, 256, 0, stream>>>(src, dst, off, eb);
  k_sortb  <<<NBKT, 256, 0, stream>>>(eb, off, rowstart, csr);
  k_gstart <<<(N_NODES + 255) / 256, 256, 0, stream>>>(batch, gstart, N_NODES);

  // ---- pool of x ----
  k_pool_x<<<N_GRAPHS, 64, 0, stream>>>(x, gstart, px);

  // ---- conv1 (in-place on A) ----
  k_agglin1<<<N_NODES / 8, 256, 0, stream>>>(csr, rowstart, x, c1_w1, c1_b1,
                                             A, stats + 0 * STREG, N_NODES);
  k_gemm64<0><<<1563, 256, 0, stream>>>(nullptr, A, stats + 0 * STREG,
      c1_g1, c1_be1, invN, c1_w2, c1_b2, A, stats + 1 * STREG, N_NODES);
  k_hpool<true><<<N_NODES / 16, 256, 0, stream>>>(A, stats + 1 * STREG, bn1_g, bn1_b,
      invN, batch, (uint2*)Hb, ph1);

  // ---- conv2 (in-place on A) ----
  k_agg64b<<<(N_NODES + 7) / 8, 256, 0, stream>>>(csr, rowstart, Hb, (float2*)A, N_NODES);
  k_gemm64<2><<<1563, 256, 0, stream>>>(Hb, A, nullptr,
      nullptr, nullptr, 0.f, c2_w1, c2_b1, A, stats + 2 * STREG, N_NODES);
  k_gemm64<0><<<1563, 256, 0, stream>>>(nullptr, A, stats + 2 * STREG,
      c2_g1, c2_be1, invN, c2_w2, c2_b2, A, stats + 3 * STREG, N_NODES);
  k_hpool<false><<<N_NODES / 16, 256, 0, stream>>>(A, stats + 3 * STREG, bn2_g, bn2_b,
      invN, batch, nullptr, ph2);

  // ---- heads ----
  k_head<<<N_GRAPHS, 64, 0, stream>>>(px, ph1, ph2, fc0_w, fc0_b, fc1_w, fc1_b,
                                      fc2_w, fc2_b, pi_w, pi_b, vf_w, vf_b, (float*)d_out);
}